// Round 8
// baseline (243.152 us; speedup 1.0000x reference)
//
#include <hip/hip_runtime.h>
#include <stdint.h>
#include <stddef.h>

typedef float    f32x4 __attribute__((ext_vector_type(4)));
typedef float    f32x2 __attribute__((ext_vector_type(2)));
typedef _Float16 f16x4 __attribute__((ext_vector_type(4)));
typedef _Float16 f16x8 __attribute__((ext_vector_type(8)));

#define HH 96
#define MROWS 16
#define OCT 136      // h1 A-layout oct stride in halves (272 B)
#define NSTR 32      // noiseTD per-t stride in dwords (16 rows x float2)
#define OSTR 100     // outLDS row stride in dwords

// 16-lane-row sum via DPP (VALU, no DS): xor1, xor2 (quad_perm), ror4, ror8
#define DPP_ADD(v, ctrl) \
    ((v) + __builtin_bit_cast(float, __builtin_amdgcn_update_dpp( \
        0, __builtin_bit_cast(int, (v)), (ctrl), 0xF, 0xF, true)))

__launch_bounds__(512, 4)
__global__ void policy_scan_kernel(
    const float* __restrict__ policy,     // (B,96,4)
    const float* __restrict__ noiseT,     // (B,96)
    const float* __restrict__ noiseD,     // (B,96)
    const float* __restrict__ action_pre, // (B,)
    const float* __restrict__ state_pre,  // (B,)
    const float* __restrict__ Lambda1,    // (1,)
    const float* __restrict__ Budget1,    // (1,)
    const float* __restrict__ W1,         // (256,6)
    const float* __restrict__ b1,         // (256,)
    const float* __restrict__ W2,         // (256,256)
    const float* __restrict__ b2,         // (256,)
    const float* __restrict__ W3,         // (256,)
    const float* __restrict__ b3,         // (1,)
    float* __restrict__ out)              // (B,96)
{
    __shared__ __attribute__((aligned(16))) float    featLDS[HH*MROWS*4];  // [t][row][4] 24576 B
    __shared__ __attribute__((aligned(16))) float    noiseTD[HH*NSTR];     // [t][row][2] 12288 B
    __shared__ __attribute__((aligned(16))) _Float16 h1LDS[32*OCT];        // 8704 B
    __shared__ __attribute__((aligned(16))) float    partialLDS[MROWS*8];  // [m][wv] 512 B
    __shared__ __attribute__((aligned(16))) float    tblLDS[HH*4];         // [t]{ft,Gam,invG,bcoef}
    __shared__ __attribute__((aligned(16))) float    outLDS[MROWS*OSTR];   // 6400 B
    // total 54016 B <= 64 KB -> 2 blocks/CU co-resident -> 4 waves/SIMD

    const int tid  = threadIdx.x;          // 0..511
    const int wv   = tid >> 6;             // 0..7  (n-chunk id, 32 neurons each)
    const int lane = tid & 63;
    const int l16  = lane & 15;
    const int lq   = lane >> 4;            // 0..3
    const int r0   = blockIdx.x * MROWS;

    // ---- stage inputs (512 threads: 3 vec4 / 3 scalar pairs each) ----
    {
        const f32x4* src = (const f32x4*)(policy + (size_t)r0 * HH * 4);
        #pragma unroll
        for (int i = 0; i < 3; ++i) {
            int idx = i*512 + tid;                 // idx = row*96 + t  (1536 total)
            int row = idx / 96, t = idx - row*96;
            *(f32x4*)&featLDS[(t*MROWS + row)*4] = src[idx];
        }
        const float* s1 = noiseT + (size_t)r0 * HH;
        const float* s2 = noiseD + (size_t)r0 * HH;
        #pragma unroll
        for (int i = 0; i < 3; ++i) {
            int idx = i*512 + tid;
            int row = idx / 96, t = idx - row*96;
            noiseTD[t*NSTR + row*2    ] = s1[idx];
            noiseTD[t*NSTR + row*2 + 1] = s2[idx];
        }
    }
    const float lam  = Lambda1[0];
    const float budH = Budget1[0] * (1.0f/96.0f);
    const float b3s  = b3[0];
    const float per_step = lam * 2.0f + budH;
    if (tid < HH) {
        float e  = __builtin_exp2f(-2.0f * (float)(95 - tid));
        float ft = 0.5f * (1.0f - e);
        float G  = 2.0f + ft;
        *(f32x4*)&tblLDS[tid*4] = f32x4{ft, G, 1.0f/G, lam*2.0f + budH*((float)tid + 2.0f)};
    }

    // ---- W2 -> fp16 B-frags: 2 n-tiles/wave (32 VGPR) ----
    // tile tt covers n = wv*32 + tt*16 + l16 ; k = kc*32 + lq*8 + j
    f16x8 bfr[2][8];
    float b2v[2], w3v[2];
    #pragma unroll
    for (int tt = 0; tt < 2; ++tt) {
        const int n = wv*32 + tt*16 + l16;
        const float* wrow = W2 + (size_t)n * 256;
        #pragma unroll
        for (int kc = 0; kc < 8; ++kc) {
            const int k0 = kc*32 + lq*8;
            f32x4 u0 = *(const f32x4*)(wrow + k0);
            f32x4 u1 = *(const f32x4*)(wrow + k0 + 4);
            f16x8 v;
            v[0]=(_Float16)u0[0]; v[1]=(_Float16)u0[1]; v[2]=(_Float16)u0[2]; v[3]=(_Float16)u0[3];
            v[4]=(_Float16)u1[0]; v[5]=(_Float16)u1[1]; v[6]=(_Float16)u1[2]; v[7]=(_Float16)u1[3];
            bfr[tt][kc] = v;
        }
        b2v[tt] = b2[n];
        w3v[tt] = W3[n];
    }

    // ---- W1 as MFMA A-frags for h1^T = W1.x^T (bias folded at k=6) ----
    f16x8 w1A[2];
    #pragma unroll
    for (int tt = 0; tt < 2; ++tt) {
        f16x8 w = {};
        if (lq == 0) {
            const int nn = wv*32 + tt*16 + l16;     // A row m' = l16 -> neuron
            #pragma unroll
            for (int j = 0; j < 6; ++j) w[j] = (_Float16)W1[nn*6 + j];
            w[6] = (_Float16)b1[nn];
        }
        w1A[tt] = w;
    }

    // h1 write: value (tt,r) -> k = wv*32+tt*16+lq*4+r, m = l16
    // addr(halves) = (k>>3)*OCT + m*8 + (k&7); r=0..3 contiguous -> b64
    const int h1wbase = (wv*4 + (lq>>1))*OCT + l16*8 + (lq&1)*4;
    const int h1r     = lq*OCT + l16*8;          // + kc*(4*OCT)

    // ---- recurrence state: lane owns row l16 (replicated across lq/wv) ----
    float stA = action_pre[r0 + l16];
    float stS = state_pre[r0 + l16];
    float stB = per_step, stC = 0.0f, stSS = 0.0f, stAD = 0.0f;
    __syncthreads();

    #pragma unroll 1
    for (int t = 0; t < HH; ++t) {
        // ---- Phase A: layer 1 via MFMA, h1^T orientation ----
        f32x4 f = *(const f32x4*)&featLDS[(t*MROWS + l16)*4];
        float dem = f[0];
        f16x8 xB = {};
        if (lq == 0) {
            xB[0]=(_Float16)f[0]; xB[1]=(_Float16)f[1];
            xB[2]=(_Float16)f[2]; xB[3]=(_Float16)f[3];
            xB[4]=(_Float16)stA;  xB[5]=(_Float16)stS;
            xB[6]=(_Float16)1.0f;
        }
        #pragma unroll
        for (int tt = 0; tt < 2; ++tt) {
            f32x4 g = {0.f,0.f,0.f,0.f};
            g = __builtin_amdgcn_mfma_f32_16x16x32_f16(w1A[tt], xB, g, 0, 0, 0);
            f16x4 hv;
            #pragma unroll
            for (int r = 0; r < 4; ++r) hv[r] = (_Float16)fmaxf(g[r], 0.0f);
            *(f16x4*)&h1LDS[h1wbase + tt*(2*OCT)] = hv;    // ds_write_b64
        }
        __syncthreads();   // bar1: h1 complete

        // ---- Phase B: layer 2, A-frag shared across 2 n-tiles; b2 folded ----
        f32x4 acc0 = f32x4{b2v[0], b2v[0], b2v[0], b2v[0]};
        f32x4 acc1 = f32x4{b2v[1], b2v[1], b2v[1], b2v[1]};
        #pragma unroll
        for (int kc = 0; kc < 8; ++kc) {
            f16x8 a = *(const f16x8*)&h1LDS[h1r + kc*(4*OCT)];
            acc0 = __builtin_amdgcn_mfma_f32_16x16x32_f16(a, bfr[0][kc], acc0, 0, 0, 0);
            acc1 = __builtin_amdgcn_mfma_f32_16x16x32_f16(a, bfr[1][kc], acc1, 0, 0, 0);
        }

        // ---- Phase C: relu, dot W3; 16-lane reduce via DPP (VALU only) ----
        #pragma unroll
        for (int r = 0; r < 4; ++r) {
            float v = fmaf(w3v[0], fmaxf(acc0[r], 0.0f), w3v[1] * fmaxf(acc1[r], 0.0f));
            v = DPP_ADD(v, 0xB1);    // quad_perm [1,0,3,2]  (xor 1)
            v = DPP_ADD(v, 0x4E);    // quad_perm [2,3,0,1]  (xor 2)
            v = DPP_ADD(v, 0x124);   // row_ror:4
            v = DPP_ADD(v, 0x128);   // row_ror:8 -> full row sum in all lanes
            if (l16 == 0) partialLDS[(lq*4 + r)*8 + wv] = v;   // [m][wv]
        }
        __syncthreads();   // bar2: partials complete

        // ---- Phase D: recurrence for row l16 (replicated in all 8 waves) ----
        f32x4 q0 = *(const f32x4*)&partialLDS[l16*8];            // wv=0..3
        f32x4 q1 = *(const f32x4*)&partialLDS[l16*8 + 4];        // wv=4..7
        f32x4 tb = *(const f32x4*)&tblLDS[t*4];                  // wave-uniform
        f32x2 nz = *(const f32x2*)&noiseTD[t*NSTR + l16*2];
        float psum = ((q0[0] + q0[1]) + (q0[2] + q0[3]))
                   + ((q1[0] + q1[1]) + (q1[2] + q1[3]));
        float a_ml   = fmaxf(psum + b3s, 0.0f);
        float a_prior = fminf(fmaxf(stS + dem, 0.0f) * 1.25f, 10.0f);
        float sgn    = (a_ml < a_prior) ? 1.0f : -1.0f;
        float a_out  = fmaf(fmaxf(fabsf(a_ml - a_prior) - stB * tb[2], 0.0f), sgn, a_ml);
        float ns     = fminf(fmaxf(stS * (1.0f - nz[1]) + dem - (0.8f + nz[0]) * a_out, 0.0f), 15.0f);
        float c_cost = fmaf(fmaf(0.1f, ns, 1.0f), ns, 2.0f);
        float ad_new = fabsf(a_out - a_prior);
        float cum_dv = fmaf(2.0f, ad_new, 0.375f * stSS);
        float c_prior = fmaxf(2.0f, c_cost - cum_dv);
        float cum_c_new = stC + (1.0f + lam) * c_prior - c_cost;
        float T      = fmaf(0.25f, stSS, ad_new);
        float cum_dg = tb[0] * T;
        float bgt_if = fmaxf(fmaxf(stB + per_step - ad_new * tb[1], 0.0f),
                             cum_c_new - cum_dg + tb[3]);
        float bgt_else = fmaxf(stB + per_step - stAD * tb[1], 0.0f);
        if (t == HH - 1) { stB = bgt_else; }
        else             { stB = bgt_if; stC = cum_c_new; }
        stSS = T;
        stAD = ad_new;
        stA  = a_out;
        stS  = ns;
        if (tid < MROWS) outLDS[tid*OSTR + t] = a_out;
        // no barrier: D's reads are bar2-protected; A(t+1) h1 writes race-free
        // (h1(t) last read in B(t) before bar2; each wave overwrites only its own slots)
    }

    // ---- coalesced output dump: 1536 dwords, 512 threads x 3 ----
    __syncthreads();
    float* oslice = out + (size_t)r0 * HH;
    #pragma unroll
    for (int i = 0; i < 3; ++i) {
        int idx = i*512 + tid;
        int row = idx / 96, c = idx - row*96;
        oslice[idx] = outLDS[row*OSTR + c];
    }
}

extern "C" void kernel_launch(void* const* d_in, const int* in_sizes, int n_in,
                              void* d_out, int out_size, void* d_ws, size_t ws_size,
                              hipStream_t stream) {
    policy_scan_kernel<<<dim3(8192 / MROWS), dim3(512), 0, stream>>>(
        (const float*)d_in[0],  // policy_in_c
        (const float*)d_in[1],  // trans_noise
        (const float*)d_in[2],  // demand_noise
        (const float*)d_in[3],  // action_pre
        (const float*)d_in[4],  // state_pre
        (const float*)d_in[5],  // Lambda
        (const float*)d_in[6],  // Budget
        (const float*)d_in[7],  // W1
        (const float*)d_in[8],  // b1
        (const float*)d_in[9],  // W2
        (const float*)d_in[10], // b2
        (const float*)d_in[11], // W3
        (const float*)d_in[12], // b3
        (float*)d_out);
}